// Round 17
// baseline (6289.671 us; speedup 1.0000x reference)
//
#include <hip/hip_runtime.h>
#include <hip/hip_bf16.h>

#define DEVI __device__ __forceinline__

namespace {

constexpr int nB = 256, nT = 64, nC = 4880, nD = 128, nH = 1024, nNT = 101, nND = 10;

typedef __attribute__((ext_vector_type(8))) short bfrag;   // 8 bf16 = 4 VGPR (MFMA A/B)
typedef __attribute__((ext_vector_type(4))) float ffrag;   // MFMA C/D
typedef __attribute__((ext_vector_type(4))) unsigned int uvec4;

DEVI ffrag mfma16(bfrag a, bfrag b, ffrag c) {
  return __builtin_amdgcn_mfma_f32_16x16x32_bf16(a, b, c, 0, 0, 0);
}

DEVI unsigned short f2b(float x) {
  __hip_bfloat16 h = __float2bfloat16(x);
  return *reinterpret_cast<unsigned short*>(&h);
}
DEVI float b2f(unsigned short u) {
  __hip_bfloat16 h;
  *reinterpret_cast<unsigned short*>(&h) = u;
  return __bfloat162float(h);
}
DEVI float sigm(float x) { return 1.f / (1.f + expf(-x)); }

// ---------------------------------------------------------------------------
// Double-buffered bf16 MFMA tile stream (VAE kernel — proven path).
// ---------------------------------------------------------------------------
template<int NS>
DEVI void mm_stream(ffrag (&acc)[NS],
                    const unsigned short* __restrict__ A, int lda, int K,
                    const unsigned short* const (&Wp)[NS], int ldw,
                    int m0, int n0, int tid, int lane, int mq, int nq,
                    unsigned short* As, unsigned short* Ws) {
  const int r = tid >> 3, blk = tid & 7;
  const int wrOff = (r * 8 + (blk ^ (r & 7))) * 8;   // ushort offset
  const int ra = mq * 16 + (lane & 15);              // A-frag row (m)
  const int rw = nq * 16 + (lane & 15);              // W-frag row (n)
  const int q = lane >> 4;                           // k-quadrant
  const int nc = K >> 6;                             // 64-wide K chunks

  uvec4 va = *(const uvec4*)(A + (size_t)(m0 + r) * lda + blk * 8);
  uvec4 vw[NS];
#pragma unroll
  for (int s = 0; s < NS; ++s)
    vw[s] = *(const uvec4*)(Wp[s] + (size_t)(n0 + r) * ldw + blk * 8);
  *(uvec4*)(As + wrOff) = va;
#pragma unroll
  for (int s = 0; s < NS; ++s) *(uvec4*)(Ws + s * 2048 + wrOff) = vw[s];

  for (int ci = 0; ci < nc; ++ci) {
    __syncthreads();
    const int cur = ci & 1;
    const bool more = (ci + 1) < nc;
    if (more) {
      const int k0 = (ci + 1) << 6;
      va = *(const uvec4*)(A + (size_t)(m0 + r) * lda + k0 + blk * 8);
#pragma unroll
      for (int s = 0; s < NS; ++s)
        vw[s] = *(const uvec4*)(Wp[s] + (size_t)(n0 + r) * ldw + k0 + blk * 8);
    }
    const unsigned short* Ab = As + cur * 2048;
    const unsigned short* Wb = Ws + cur * (NS * 2048);
#pragma unroll
    for (int kk = 0; kk < 2; ++kk) {
      bfrag af = *(const bfrag*)(Ab + (ra * 8 + ((kk * 4 + q) ^ (ra & 7))) * 8);
#pragma unroll
      for (int s = 0; s < NS; ++s) {
        bfrag wf = *(const bfrag*)(Wb + s * 2048 + (rw * 8 + ((kk * 4 + q) ^ (rw & 7))) * 8);
        acc[s] = mfma16(af, wf, acc[s]);
      }
    }
    if (more) {
      const int nx = cur ^ 1;
      *(uvec4*)(As + nx * 2048 + wrOff) = va;
#pragma unroll
      for (int s = 0; s < NS; ++s)
        *(uvec4*)(Ws + nx * (NS * 2048) + s * 2048 + wrOff) = vw[s];
    }
  }
  __syncthreads();
}

// ---- fp32 -> bf16 bulk convert (n divisible by 1024) ----
__global__ void k_cvt(const float* __restrict__ s, unsigned short* __restrict__ d, int n) {
  int i = blockIdx.x * blockDim.x + threadIdx.x;
  float4 v = ((const float4*)s)[i];
  unsigned int u0 = (unsigned int)f2b(v.x) | ((unsigned int)f2b(v.y) << 16);
  unsigned int u1 = (unsigned int)f2b(v.z) | ((unsigned int)f2b(v.w) << 16);
  ((uint2*)d)[i] = make_uint2(u0, u1);
}

// ---- LLM diagnosis mask ----
__global__ void k_mask(const int* __restrict__ llm, float* __restrict__ outm) {
  int c = blockIdx.x * 256 + threadIdx.x;
  int b = blockIdx.y;
  if (c >= nC) return;
  const int* lr = llm + b * nND;
  float v = 0.f;
#pragma unroll
  for (int i = 0; i < nND; ++i) v = (lr[i] == c) ? 1.f : v;
  outm[(size_t)b * nC + c] = v;
}

// ---- sparse visit embedding ----
__global__ void k_embed(const float* __restrict__ Hs, const float* __restrict__ emb,
                        unsigned short* __restrict__ ve) {
  __shared__ float tile[4][16][128];
  const int b = blockIdx.x;
  const int tid = threadIdx.x;
  const int w = tid >> 6, lane = tid & 63;
  float* tw = &tile[w][0][0];
  for (int i = lane; i < 16 * 128; i += 64) tw[i] = 0.f;
  const float* hb = Hs + (size_t)b * nC * nT;
  const int tq = w * 16;
  const int tl = lane & 15;
  const int co = lane >> 4;
  for (int cb = 0; cb < nC; cb += 4) {
    const int c = cb + co;
    float v = hb[(size_t)c * nT + tq + tl];
    unsigned long long m = __ballot(v != 0.f);
    while (m) {
      const int p = __ffsll(m) - 1;
      m &= m - 1;
      const int cc = cb + (p >> 4);
      const int tt = p & 15;
      const float vv = __shfl(v, p);
      const float* er = emb + (size_t)cc * nD;
      tile[w][tt][lane]      += vv * er[lane];
      tile[w][tt][lane + 64] += vv * er[lane + 64];
    }
  }
  for (int rr = 0; rr < 16; ++rr) {
    unsigned short* o = ve + ((size_t)b * nT + tq + rr) * nD;
    o[lane]      = f2b(tile[w][rr][lane]);
    o[lane + 64] = f2b(tile[w][rr][lane + 64]);
  }
}

// ---- attention pooling ----
__global__ void k_attn(const unsigned short* __restrict__ hsb,
                       const float* __restrict__ aw,
                       unsigned short* __restrict__ hencb) {
  __shared__ float sc[nT];
  __shared__ float al[nT];
  const int b = blockIdx.x;
  const int tid = threadIdx.x;
  const int w = tid >> 6, lane = tid & 63;
  for (int t = w; t < nT; t += 4) {
    const unsigned short* hr = hsb + ((size_t)b * nT + t) * nH;
    float s = 0.f;
    for (int i = lane; i < nH; i += 64) s += b2f(hr[i]) * aw[i];
#pragma unroll
    for (int o = 32; o > 0; o >>= 1) s += __shfl_xor(s, o);
    if (lane == 0) sc[t] = s;
  }
  __syncthreads();
  if (tid < nT) {
    float v = sc[tid];
    float mx = v;
#pragma unroll
    for (int o = 32; o > 0; o >>= 1) mx = fmaxf(mx, __shfl_xor(mx, o));
    float e = expf(v - mx);
    float su = e;
#pragma unroll
    for (int o = 32; o > 0; o >>= 1) su += __shfl_xor(su, o);
    al[tid] = e / su;
  }
  __syncthreads();
  for (int col = tid; col < nH; col += 256) {
    float a = 0.f;
    for (int t = 0; t < nT; ++t) a += al[t] * b2f(hsb[((size_t)b * nT + t) * nH + col]);
    hencb[(size_t)b * nH + col] = f2b(a);
  }
}

// ---- VAE head ----
__global__ __launch_bounds__(256) void k_vae(
    const unsigned short* __restrict__ hencb,
    const unsigned short* __restrict__ Wmu, const unsigned short* __restrict__ Wvar,
    const float* __restrict__ bmu, const float* __restrict__ bvar,
    const float* __restrict__ eps,
    float* __restrict__ hf, unsigned short* __restrict__ hb,
    const int* __restrict__ lidx, float* __restrict__ out) {
  __shared__ __align__(16) unsigned short As[2 * 2048];
  __shared__ __align__(16) unsigned short Ws[2 * 2 * 2048];
  const int tid = threadIdx.x, lane = tid & 63, w = tid >> 6;
  const int mq = w & 1, nq = w >> 1;
  const int m0 = blockIdx.x * 32, n0 = blockIdx.y * 32;
  ffrag acc[2] = {};
  const unsigned short* const Wp[2] = {Wmu, Wvar};
  mm_stream<2>(acc, hencb, nH, nH, Wp, nH, m0, n0, tid, lane, mq, nq, As, Ws);
  const int col = n0 + nq * 16 + (lane & 15);
  const int rb = m0 + mq * 16 + ((lane >> 4) << 2);
#pragma unroll
  for (int i = 0; i < 4; ++i) {
    const int row = rb + i;
    const size_t idx = (size_t)row * nH + col;
    const float mu = acc[0][i] + bmu[col];
    const float lv = acc[1][i] + bvar[col];
    const float z0 = mu + expf(0.5f * lv) * eps[idx];
    hf[idx] = z0;
    hb[idx] = f2b(z0);
    if (lidx[row] == 0) out[idx] = z0;  // pred_z[b, 0]
  }
}

// ---------------------------------------------------------------------------
// Shared persistent machinery (round 8/14, proven).
// ---------------------------------------------------------------------------
DEVI void rb_bar(unsigned* c, unsigned tgt) {   // GRU full barrier (round 14)
  asm volatile("s_waitcnt vmcnt(0)" ::: "memory");
  __syncthreads();
  if (threadIdx.x == 0) {
    __hip_atomic_fetch_add(c, 1u, __ATOMIC_RELAXED, __HIP_MEMORY_SCOPE_AGENT);
    while (__hip_atomic_load(c, __ATOMIC_RELAXED, __HIP_MEMORY_SCOPE_AGENT) < tgt)
      __builtin_amdgcn_s_sleep(2);
  }
  __syncthreads();
}

// split barrier halves for the pipelined ODE (same primitives)
DEVI void cp_arrive(unsigned* c) {
  if (threadIdx.x == 0)
    __hip_atomic_fetch_add(c, 1u, __ATOMIC_RELAXED, __HIP_MEMORY_SCOPE_AGENT);
}
DEVI void cp_wait(unsigned* c, unsigned tgt) {
  if (threadIdx.x == 0) {
    while (__hip_atomic_load(c, __ATOMIC_RELAXED, __HIP_MEMORY_SCOPE_AGENT) < tgt)
      __builtin_amdgcn_s_sleep(2);
  }
  __syncthreads();
}

DEVI void stageW(const unsigned short* __restrict__ Wg, int n0, int tid,
                 unsigned short* Ws) {
  const int r = tid >> 3, b0 = tid & 7;
  const unsigned short* src = Wg + (size_t)(n0 + r) * nH;
  unsigned short* dst = Ws + r * 1024;
#pragma unroll
  for (int t2 = 0; t2 < 16; ++t2) {
    const int blk = b0 + 8 * t2;
    *(uvec4*)(dst + (blk ^ (r & 7)) * 8) = *(const uvec4*)(src + blk * 8);
  }
}

// 8 A-fragments via sc0 loads (XCD L2); waitcnt INSIDE the asm.
DEVI void ld8w(uvec4 (&d)[8], const unsigned short* p) {
  asm volatile(
      "global_load_dwordx4 %0, %8, off sc0\n\t"
      "global_load_dwordx4 %1, %8, off offset:64 sc0\n\t"
      "global_load_dwordx4 %2, %8, off offset:128 sc0\n\t"
      "global_load_dwordx4 %3, %8, off offset:192 sc0\n\t"
      "global_load_dwordx4 %4, %8, off offset:256 sc0\n\t"
      "global_load_dwordx4 %5, %8, off offset:320 sc0\n\t"
      "global_load_dwordx4 %6, %8, off offset:384 sc0\n\t"
      "global_load_dwordx4 %7, %8, off offset:448 sc0\n\t"
      "s_waitcnt vmcnt(0)"
      : "=&v"(d[0]), "=&v"(d[1]), "=&v"(d[2]), "=&v"(d[3]),
        "=&v"(d[4]), "=&v"(d[5]), "=&v"(d[6]), "=&v"(d[7])
      : "v"(p)
      : "memory");
}

// full-K 32x32 matmul (GRU path, proven round 8)
DEVI ffrag mm_l2(const unsigned short* ag, const unsigned short* wrow,
                 int q, int rx) {
  ffrag a0 = {0.f, 0.f, 0.f, 0.f}, a1 = {0.f, 0.f, 0.f, 0.f};
#pragma unroll
  for (int g = 0; g < 4; ++g) {
    uvec4 A[8];
    ld8w(A, ag + g * 256);
#pragma unroll
    for (int k8 = 0; k8 < 8; k8 += 2) {
      const int kk = g * 8 + k8;
      a0 = mfma16(*(const bfrag*)&A[k8],
                  *(const bfrag*)(wrow + (((kk * 4 + q) ^ rx) * 8)), a0);
      a1 = mfma16(*(const bfrag*)&A[k8 + 1],
                  *(const bfrag*)(wrow + ((((kk + 1) * 4 + q) ^ rx) * 8)), a1);
    }
  }
  return a0 + a1;
}

// half-K (512) 16-row matmul for the pipelined ODE: kq selects the K half.
DEVI ffrag mm_half(const unsigned short* ag, const unsigned short* wrow,
                   int q, int rx, int kq) {
  ffrag a0 = {0.f, 0.f, 0.f, 0.f}, a1 = {0.f, 0.f, 0.f, 0.f};
#pragma unroll
  for (int g = 0; g < 2; ++g) {
    uvec4 A[8];
    ld8w(A, ag + kq * 512 + g * 256);
#pragma unroll
    for (int k8 = 0; k8 < 8; k8 += 2) {
      const int kk = kq * 16 + g * 8 + k8;
      a0 = mfma16(*(const bfrag*)&A[k8],
                  *(const bfrag*)(wrow + (((kk * 4 + q) ^ rx) * 8)), a0);
      a1 = mfma16(*(const bfrag*)&A[k8 + 1],
                  *(const bfrag*)(wrow + ((((kk + 1) * 4 + q) ^ rx) * 8)), a1);
    }
  }
  return a0 + a1;
}

// Repack a wave's 16x16 C-tile through wave-private LDS into row-contiguous
// 8B chunks; plain stores (write-through to XCD L2).
DEVI void pack_store(const float v[4], unsigned short* pkw, int lane,
                     unsigned short* dst /* tile base, ld=nH */) {
  const int cl = lane & 15, r0l = (lane >> 4) << 2;
#pragma unroll
  for (int i = 0; i < 4; ++i) pkw[(r0l + i) * 16 + cl] = f2b(v[i]);
  asm volatile("s_waitcnt lgkmcnt(0)" ::: "memory");
  __builtin_amdgcn_sched_barrier(0);                  // rule #18
  const int pr = lane >> 2, pc = (lane & 3) << 2;
  *(unsigned long long*)(dst + pr * nH + pc) =
      *(const unsigned long long*)(pkw + pr * 16 + pc);
}

DEVI void pack_store2(const float v[4], unsigned short* pkw, int lane,
                      unsigned short* d1, unsigned short* d2) {
  const int cl = lane & 15, r0l = (lane >> 4) << 2;
#pragma unroll
  for (int i = 0; i < 4; ++i) pkw[(r0l + i) * 16 + cl] = f2b(v[i]);
  asm volatile("s_waitcnt lgkmcnt(0)" ::: "memory");
  __builtin_amdgcn_sched_barrier(0);
  const int pr = lane >> 2, pc = (lane & 3) << 2;
  const unsigned long long val = *(const unsigned long long*)(pkw + pr * 16 + pc);
  *(unsigned long long*)(d1 + (size_t)pr * nH + pc) = val;
  *(unsigned long long*)(d2 + (size_t)pr * (nT * nH) + pc) = val;
}

// ---------------------------------------------------------------------------
// Persistent 64-step GRU (round-14 proven, unchanged).
// ---------------------------------------------------------------------------
__global__ __launch_bounds__(256, 1) void k_gru_persist(
    const unsigned short* __restrict__ Whh_g, const unsigned short* __restrict__ Wih_g,
    const float* __restrict__ bih, const float* __restrict__ bhh,
    const unsigned short* __restrict__ ve,
    unsigned short* hA, unsigned short* hB,
    unsigned short* hsb, unsigned* ctr) {
  __shared__ __align__(16) unsigned short Wr[32 * nH];
  __shared__ __align__(16) unsigned short Wz2[32 * nH];
  __shared__ __align__(16) unsigned short Wi[96 * nD];
  __shared__ __align__(16) unsigned short pk[4][16][16];
  __shared__ unsigned rank_sh;
  const int tid = threadIdx.x, lane = tid & 63, w = tid >> 6;
  const int mq = w & 1, nq = w >> 1;

  unsigned xcd;
  asm volatile("s_getreg_b32 %0, hwreg(HW_REG_XCC_ID)" : "=s"(xcd));
  if (tid == 0)
    rank_sh = __hip_atomic_fetch_add(ctr + 1536 + (xcd & 7) * 16, 1u,
                                     __ATOMIC_RELAXED, __HIP_MEMORY_SCOPE_AGENT);
  __syncthreads();
  const int i = (int)(xcd & 7);
  const int j = (int)(rank_sh & 31);
  const int m0 = i * 32, n0 = j * 32;

  stageW(Whh_g, n0, tid, Wr);
  stageW(Whh_g + (size_t)nH * nH, n0, tid, Wz2);
  for (int idx = tid; idx < 96 * 16; idx += 256) {
    const int r = idx >> 4, blk = idx & 15;
    const int gate = r >> 5, rr2 = r & 31;
    *(uvec4*)(Wi + r * nD + ((blk ^ (r & 7)) * 8)) =
        *(const uvec4*)(Wih_g + ((size_t)gate * nH + n0 + rr2) * nD + blk * 8);
  }

  const int col = n0 + nq * 16 + (lane & 15);
  const int arow = m0 + mq * 16 + (lane & 15);
  const int q = lane >> 4;
  const int rw = nq * 16 + (lane & 15);
  const int rx = rw & 7;
  const unsigned short* wrr = Wr + rw * nH;
  const unsigned short* wzr = Wz2 + rw * nH;
  const unsigned short* wir = Wi + rw * nD;
  const unsigned short* wiz = Wi + (32 + rw) * nD;
  const unsigned short* win = Wi + (64 + rw) * nD;
  const unsigned short* wng = Whh_g + ((size_t)2 * nH + col) * nH + q * 8;
  const unsigned short* aA = hA + (size_t)arow * nH + q * 8;
  const unsigned short* aB = hB + (size_t)arow * nH + q * 8;
  unsigned short* dA = hA + (size_t)(m0 + mq * 16) * nH + n0 + nq * 16;
  unsigned short* dB = hB + (size_t)(m0 + mq * 16) * nH + n0 + nq * 16;
  unsigned short* dh = hsb + (size_t)(m0 + mq * 16) * nT * nH + n0 + nq * 16;
  unsigned short* pkw = &pk[w][0][0];
  const float b_r = bih[col] + bhh[col];
  const float b_z = bih[nH + col] + bhh[nH + col];
  const float bi_n = bih[2 * nH + col];
  const float bh_n = bhh[2 * nH + col];

  float hf_[4] = {0.f, 0.f, 0.f, 0.f};
  unsigned* myc = ctr + 1024 + i * 64;
  unsigned ph = 0;
  __syncthreads();

#pragma unroll 1
  for (int t = 0; t < nT; ++t) {
    const unsigned short* ah = (t & 1) ? aB : aA;
    unsigned short* dst = (t & 1) ? dA : dB;
    ffrag ar = {0.f, 0.f, 0.f, 0.f}, az = {0.f, 0.f, 0.f, 0.f},
          an = {0.f, 0.f, 0.f, 0.f};
#pragma unroll
    for (int g = 0; g < 4; ++g) {
      uvec4 A[8];
      ld8w(A, ah + g * 256);
#pragma unroll
      for (int k8 = 0; k8 < 8; ++k8) {
        const int kk = g * 8 + k8;
        const int wo = ((kk * 4 + q) ^ rx) * 8;
        const bfrag af = *(const bfrag*)&A[k8];
        ar = mfma16(af, *(const bfrag*)(wrr + wo), ar);
        az = mfma16(af, *(const bfrag*)(wzr + wo), az);
        an = mfma16(af, *(const bfrag*)(wng + kk * 32), an);
      }
    }
    ffrag ir = {0.f, 0.f, 0.f, 0.f}, iz = {0.f, 0.f, 0.f, 0.f},
          in_ = {0.f, 0.f, 0.f, 0.f};
    const unsigned short* av = ve + ((size_t)arow * nT + t) * nD + q * 8;
#pragma unroll
    for (int kk = 0; kk < 4; ++kk) {
      const bfrag af = *(const bfrag*)(av + kk * 32);
      const int wo = ((kk * 4 + q) ^ rx) * 8;
      ir = mfma16(af, *(const bfrag*)(wir + wo), ir);
      iz = mfma16(af, *(const bfrag*)(wiz + wo), iz);
      in_ = mfma16(af, *(const bfrag*)(win + wo), in_);
    }
    float hv[4];
#pragma unroll
    for (int ii = 0; ii < 4; ++ii) {
      const float rr2 = sigm(ar[ii] + ir[ii] + b_r);
      const float zv = sigm(az[ii] + iz[ii] + b_z);
      const float nn = tanhf(in_[ii] + bi_n + rr2 * (an[ii] + bh_n));
      const float hn2 = (1.f - zv) * nn + zv * hf_[ii];
      hf_[ii] = hn2;
      hv[ii] = hn2;
    }
    pack_store2(hv, pkw, lane, dst, dh + (size_t)t * nH);
    ph += 32; rb_bar(myc, ph);
  }
}

// ---------------------------------------------------------------------------
// Persistent GRU-ODE RK4, take 11: 2-STREAM SOFTWARE PIPELINING.
// XCD's 32 rows split into half-bands A (rows+0..16) and B (+16..32); both
// share the block's 32-col W slices (same LDS). Per RK4 stage the block runs
// A and B interleaved so every CP wait is preceded by ~1.2us of the other
// stream's compute (waits gate on arrivals made one mm-let earlier by all
// blocks -> CP visibility hidden). Arrive/wait = round-8-proven fetch_add /
// atomic_load halves. Single g/x buffers safe: writer of phase p+1 passed a
// wait that transitively implies all readers of phase p finished (vmcnt
// drains loads before arrive). 16-row matmuls use 2-way K-split across wave
// pairs (kq = w&1) with padded-LDS f32 reduce.
// ---------------------------------------------------------------------------
__global__ __launch_bounds__(256, 1) void k_ode_persist(
    const unsigned short* __restrict__ Wz_g, const unsigned short* __restrict__ Wn_g,
    const float* __restrict__ h0f, unsigned short* xb, unsigned short* gbuf,
    const float* __restrict__ ts, const int* __restrict__ lidx,
    float* __restrict__ out, unsigned* ctr) {
  __shared__ __align__(16) unsigned short Wz[32 * nH];     // 64 KB
  __shared__ __align__(16) unsigned short Wn[32 * nH];     // 64 KB
  __shared__ __align__(16) unsigned short pk[4][16][16];   // pack tiles
  __shared__ float red[2][16][17];                         // k-split reduce
  __shared__ unsigned rank_sh;
  const int tid = threadIdx.x, lane = tid & 63, w = tid >> 6;
  const int kq = w & 1, nq = w >> 1;     // kq: K half; nq: 16-col subtile

  unsigned xcd;
  asm volatile("s_getreg_b32 %0, hwreg(HW_REG_XCC_ID)" : "=s"(xcd));
  if (tid == 0)
    rank_sh = __hip_atomic_fetch_add(ctr + 2048 + (xcd & 7) * 16, 1u,
                                     __ATOMIC_RELAXED, __HIP_MEMORY_SCOPE_AGENT);
  __syncthreads();
  const int ix = (int)(xcd & 7);
  const int j = (int)(rank_sh & 31);
  const int n0 = j * 32;
  const int rowA = ix * 32, rowB = rowA + 16;

  stageW(Wz_g, n0, tid, Wz);
  stageW(Wn_g, n0, tid, Wn);

  const int col = n0 + nq * 16 + (lane & 15);
  const int q = lane >> 4;
  const int rl4 = (lane >> 4) << 2;
  const int rw = nq * 16 + (lane & 15);
  const int rx = rw & 7;
  const unsigned short* wzrow = Wz + rw * nH;
  const unsigned short* wnrow = Wn + rw * nH;
  const unsigned short* axA = xb + (size_t)(rowA + (lane & 15)) * nH + q * 8;
  const unsigned short* axB = xb + (size_t)(rowB + (lane & 15)) * nH + q * 8;
  const unsigned short* agA = gbuf + (size_t)(rowA + (lane & 15)) * nH + q * 8;
  const unsigned short* agB = gbuf + (size_t)(rowB + (lane & 15)) * nH + q * 8;
  unsigned short* pkw = &pk[w][0][0];
  unsigned short* gdA = gbuf + (size_t)rowA * nH + n0 + nq * 16;
  unsigned short* gdB = gbuf + (size_t)rowB * nH + n0 + nq * 16;
  unsigned short* xdA = xb + (size_t)rowA * nH + n0 + nq * 16;
  unsigned short* xdB = xb + (size_t)rowB * nH + n0 + nq * 16;

  // per-stream RK4 state (meaningful in kq==0 waves)
  float hbA[4], xvA[4], kaA[4], zvA[4];
  float hbB[4], xvB[4], kaB[4], zvB[4];
  int lstA[4], lstB[4];
  const int row0A = rowA + rl4, row0B = rowB + rl4;
#pragma unroll
  for (int ii = 0; ii < 4; ++ii) {
    hbA[ii] = h0f[(size_t)(row0A + ii) * nH + col];
    xvA[ii] = hbA[ii];
    lstA[ii] = lidx[row0A + ii];
    hbB[ii] = h0f[(size_t)(row0B + ii) * nH + col];
    xvB[ii] = hbB[ii];
    lstB[ii] = lidx[row0B + ii];
  }
  unsigned* cA = ctr + (ix * 2 + 0) * 64;
  unsigned* cB = ctr + (ix * 2 + 1) * 64;
  unsigned base = 0;
  __syncthreads();   // weights staged

#define MM1_LET(AX, GD, ZV, XV)                                           \
  {                                                                       \
    ffrag acc = mm_half(AX, wzrow, q, rx, kq);                            \
    if (kq == 1) {                                                        \
      _Pragma("unroll")                                                   \
      for (int ii = 0; ii < 4; ++ii) red[nq][rl4 + ii][lane & 15] = acc[ii]; \
    }                                                                     \
    __syncthreads();                                                      \
    if (kq == 0) {                                                        \
      float gv[4];                                                        \
      _Pragma("unroll")                                                   \
      for (int ii = 0; ii < 4; ++ii) {                                    \
        acc[ii] += red[nq][rl4 + ii][lane & 15];                          \
        ZV[ii] = sigm(acc[ii]);                                           \
        gv[ii] = ZV[ii] * XV[ii];                                         \
      }                                                                   \
      pack_store(gv, pkw, lane, GD);                                      \
      asm volatile("s_waitcnt vmcnt(0)" ::: "memory");                    \
    }                                                                     \
    __syncthreads();                                                      \
  }

#define MM2_LET(AG, XD, ZV, XV, HB, KA, LST, ROW0)                        \
  {                                                                       \
    ffrag acc = mm_half(AG, wnrow, q, rx, kq);                            \
    if (kq == 1) {                                                        \
      _Pragma("unroll")                                                   \
      for (int ii = 0; ii < 4; ++ii) red[nq][rl4 + ii][lane & 15] = acc[ii]; \
    }                                                                     \
    __syncthreads();                                                      \
    if (kq == 0) {                                                        \
      _Pragma("unroll")                                                   \
      for (int ii = 0; ii < 4; ++ii) {                                    \
        acc[ii] += red[nq][rl4 + ii][lane & 15];                          \
        const float nn = tanhf(acc[ii]);                                  \
        const float fv = (1.f - ZV[ii]) * (nn - XV[ii]);                  \
        if (stg == 0)      { KA[ii] = fv;        XV[ii] = HB[ii] + 0.5f * dt * fv; } \
        else if (stg == 1) { KA[ii] += 2.f * fv; XV[ii] = HB[ii] + 0.5f * dt * fv; } \
        else if (stg == 2) { KA[ii] += 2.f * fv; XV[ii] = HB[ii] + dt * fv; } \
        else {                                                            \
          const float hn = HB[ii] + (dt * (1.f / 6.f)) * (KA[ii] + fv);   \
          HB[ii] = hn; XV[ii] = hn;                                       \
          if (LST[ii] == s + 1) out[(size_t)(ROW0 + ii) * nH + col] = hn; \
        }                                                                 \
      }                                                                   \
      pack_store(XV, pkw, lane, XD);                                      \
      asm volatile("s_waitcnt vmcnt(0)" ::: "memory");                    \
    }                                                                     \
    __syncthreads();                                                      \
  }

#pragma unroll 1
  for (int p = 0; p < 4 * (nNT - 1); ++p) {
    const int s = p >> 2, stg = p & 3;
    const float dt = ts[s + 1] - ts[s];
    cp_wait(cA, base);                 // xA(p) ready
    MM1_LET(axA, gdA, zvA, xvA)
    cp_arrive(cA);
    cp_wait(cB, base);                 // xB(p) ready (overlapped w/ mm1_A)
    MM1_LET(axB, gdB, zvB, xvB)
    cp_arrive(cB);
    cp_wait(cA, base + 32);            // gA ready (overlapped w/ mm1_B)
    MM2_LET(agA, xdA, zvA, xvA, hbA, kaA, lstA, row0A)
    cp_arrive(cA);
    cp_wait(cB, base + 32);            // gB ready (overlapped w/ mm2_A)
    MM2_LET(agB, xdB, zvB, xvB, hbB, kaB, lstB, row0B)
    cp_arrive(cB);
    base += 64;
  }
#undef MM1_LET
#undef MM2_LET
}

}  // namespace

extern "C" void kernel_launch(void* const* d_in, const int* in_sizes, int n_in,
                              void* d_out, int out_size, void* d_ws, size_t ws_size,
                              hipStream_t stream) {
  const float* Hs   = (const float*)d_in[0];
  const float* ts   = (const float*)d_in[1];
  const int*   lidx = (const int*)d_in[2];
  const int*   llm  = (const int*)d_in[3];
  const float* eps  = (const float*)d_in[4];
  const float* emb  = (const float*)d_in[5];
  const float* Wih  = (const float*)d_in[6];
  const float* Whh  = (const float*)d_in[7];
  const float* bih  = (const float*)d_in[8];
  const float* bhh  = (const float*)d_in[9];
  const float* aw   = (const float*)d_in[10];
  const float* Wmu  = (const float*)d_in[11];
  const float* bmu  = (const float*)d_in[12];
  const float* Wvar = (const float*)d_in[13];
  const float* bvar = (const float*)d_in[14];
  const float* Whz  = (const float*)d_in[15];
  const float* Whn  = (const float*)d_in[16];

  float* out_last = (float*)d_out;
  float* out_mask = out_last + (size_t)nB * nH;

  char* p = (char*)d_ws;
  auto alloc = [&](size_t bytes) {
    void* r = p; p += (bytes + 255) & ~(size_t)255; return r;
  };
  unsigned short* Whh_b  = (unsigned short*)alloc((size_t)3 * nH * nH * 2);
  unsigned short* Wih_b  = (unsigned short*)alloc((size_t)3 * nH * nD * 2);
  unsigned short* Wmu_b  = (unsigned short*)alloc((size_t)nH * nH * 2);
  unsigned short* Wvar_b = (unsigned short*)alloc((size_t)nH * nH * 2);
  unsigned short* Whz_b  = (unsigned short*)alloc((size_t)nH * nH * 2);
  unsigned short* Whn_b  = (unsigned short*)alloc((size_t)nH * nH * 2);
  unsigned short* ve_b   = (unsigned short*)alloc((size_t)nB * nT * nD * 2);
  unsigned short* hs_b   = (unsigned short*)alloc((size_t)nB * nT * nH * 2);
  float* h0f             = (float*)alloc((size_t)nB * nH * 4);
  unsigned short* h0b    = (unsigned short*)alloc((size_t)nB * nH * 2);
  unsigned short* h1b    = (unsigned short*)alloc((size_t)nB * nH * 2);
  unsigned short* gb     = (unsigned short*)alloc((size_t)nB * nH * 2);
  unsigned short* hencb  = (unsigned short*)alloc((size_t)nB * nH * 2);
  unsigned* ctr          = (unsigned*)alloc(16384);  // counters/flags

  hipMemsetAsync(h0b, 0, (size_t)nB * nH * 2, stream);   // GRU h0 = 0
  hipMemsetAsync(ctr, 0, 16384, stream);                 // all counters

  auto cvt = [&](const float* s, unsigned short* d, int n) {
    k_cvt<<<n / 1024, 256, 0, stream>>>(s, d, n);
  };
  cvt(Whh, Whh_b, 3 * nH * nH);
  cvt(Wih, Wih_b, 3 * nH * nD);
  cvt(Wmu, Wmu_b, nH * nH);
  cvt(Wvar, Wvar_b, nH * nH);
  cvt(Whz, Whz_b, nH * nH);
  cvt(Whn, Whn_b, nH * nH);

  k_embed<<<nB, 256, 0, stream>>>(Hs, emb, ve_b);
  k_mask<<<dim3((nC + 255) / 256, nB), 256, 0, stream>>>(llm, out_mask);

  // entire 64-step GRU in one persistent kernel (round-14 proven)
  k_gru_persist<<<256, 256, 0, stream>>>(Whh_b, Wih_b, bih, bhh, ve_b,
                                         h0b, h1b, hs_b, ctr);

  k_attn<<<nB, 256, 0, stream>>>(hs_b, aw, hencb);
  const dim3 gg(nB / 32, nH / 32);  // 8 x 32 = 256 blocks
  // z0 -> h0f (f32 base state) + h0b (bf16, first mm1 A-operand)
  k_vae<<<gg, 256, 0, stream>>>(hencb, Wmu_b, Wvar_b, bmu, bvar, eps,
                                h0f, h0b, lidx, out_last);

  // 100-step RK4 GRU-ODE, 2-stream pipelined persistent kernel
  k_ode_persist<<<256, 256, 0, stream>>>(Whz_b, Whn_b, h0f, h0b, gb, ts, lidx,
                                         out_last, ctr);
}

// Round 18
// 5395.473 us; speedup vs baseline: 1.1657x; 1.1657x over previous
//
#include <hip/hip_runtime.h>
#include <hip/hip_bf16.h>

#define DEVI __device__ __forceinline__

namespace {

constexpr int nB = 256, nT = 64, nC = 4880, nD = 128, nH = 1024, nNT = 101, nND = 10;

typedef __attribute__((ext_vector_type(8))) short bfrag;   // 8 bf16 = 4 VGPR (MFMA A/B)
typedef __attribute__((ext_vector_type(4))) float ffrag;   // MFMA C/D
typedef __attribute__((ext_vector_type(4))) unsigned int uvec4;

DEVI ffrag mfma16(bfrag a, bfrag b, ffrag c) {
  return __builtin_amdgcn_mfma_f32_16x16x32_bf16(a, b, c, 0, 0, 0);
}

DEVI unsigned short f2b(float x) {
  __hip_bfloat16 h = __float2bfloat16(x);
  return *reinterpret_cast<unsigned short*>(&h);
}
DEVI float b2f(unsigned short u) {
  __hip_bfloat16 h;
  *reinterpret_cast<unsigned short*>(&h) = u;
  return __bfloat162float(h);
}
DEVI float sigm(float x) { return 1.f / (1.f + expf(-x)); }

// ---------------------------------------------------------------------------
// Double-buffered bf16 MFMA tile stream (VAE kernel — proven path).
// ---------------------------------------------------------------------------
template<int NS>
DEVI void mm_stream(ffrag (&acc)[NS],
                    const unsigned short* __restrict__ A, int lda, int K,
                    const unsigned short* const (&Wp)[NS], int ldw,
                    int m0, int n0, int tid, int lane, int mq, int nq,
                    unsigned short* As, unsigned short* Ws) {
  const int r = tid >> 3, blk = tid & 7;
  const int wrOff = (r * 8 + (blk ^ (r & 7))) * 8;   // ushort offset
  const int ra = mq * 16 + (lane & 15);              // A-frag row (m)
  const int rw = nq * 16 + (lane & 15);              // W-frag row (n)
  const int q = lane >> 4;                           // k-quadrant
  const int nc = K >> 6;                             // 64-wide K chunks

  uvec4 va = *(const uvec4*)(A + (size_t)(m0 + r) * lda + blk * 8);
  uvec4 vw[NS];
#pragma unroll
  for (int s = 0; s < NS; ++s)
    vw[s] = *(const uvec4*)(Wp[s] + (size_t)(n0 + r) * ldw + blk * 8);
  *(uvec4*)(As + wrOff) = va;
#pragma unroll
  for (int s = 0; s < NS; ++s) *(uvec4*)(Ws + s * 2048 + wrOff) = vw[s];

  for (int ci = 0; ci < nc; ++ci) {
    __syncthreads();
    const int cur = ci & 1;
    const bool more = (ci + 1) < nc;
    if (more) {
      const int k0 = (ci + 1) << 6;
      va = *(const uvec4*)(A + (size_t)(m0 + r) * lda + k0 + blk * 8);
#pragma unroll
      for (int s = 0; s < NS; ++s)
        vw[s] = *(const uvec4*)(Wp[s] + (size_t)(n0 + r) * ldw + k0 + blk * 8);
    }
    const unsigned short* Ab = As + cur * 2048;
    const unsigned short* Wb = Ws + cur * (NS * 2048);
#pragma unroll
    for (int kk = 0; kk < 2; ++kk) {
      bfrag af = *(const bfrag*)(Ab + (ra * 8 + ((kk * 4 + q) ^ (ra & 7))) * 8);
#pragma unroll
      for (int s = 0; s < NS; ++s) {
        bfrag wf = *(const bfrag*)(Wb + s * 2048 + (rw * 8 + ((kk * 4 + q) ^ (rw & 7))) * 8);
        acc[s] = mfma16(af, wf, acc[s]);
      }
    }
    if (more) {
      const int nx = cur ^ 1;
      *(uvec4*)(As + nx * 2048 + wrOff) = va;
#pragma unroll
      for (int s = 0; s < NS; ++s)
        *(uvec4*)(Ws + nx * (NS * 2048) + s * 2048 + wrOff) = vw[s];
    }
  }
  __syncthreads();
}

// ---- fp32 -> bf16 bulk convert (n divisible by 1024) ----
__global__ void k_cvt(const float* __restrict__ s, unsigned short* __restrict__ d, int n) {
  int i = blockIdx.x * blockDim.x + threadIdx.x;
  float4 v = ((const float4*)s)[i];
  unsigned int u0 = (unsigned int)f2b(v.x) | ((unsigned int)f2b(v.y) << 16);
  unsigned int u1 = (unsigned int)f2b(v.z) | ((unsigned int)f2b(v.w) << 16);
  ((uint2*)d)[i] = make_uint2(u0, u1);
}

// ---- LLM diagnosis mask ----
__global__ void k_mask(const int* __restrict__ llm, float* __restrict__ outm) {
  int c = blockIdx.x * 256 + threadIdx.x;
  int b = blockIdx.y;
  if (c >= nC) return;
  const int* lr = llm + b * nND;
  float v = 0.f;
#pragma unroll
  for (int i = 0; i < nND; ++i) v = (lr[i] == c) ? 1.f : v;
  outm[(size_t)b * nC + c] = v;
}

// ---- sparse visit embedding ----
__global__ void k_embed(const float* __restrict__ Hs, const float* __restrict__ emb,
                        unsigned short* __restrict__ ve) {
  __shared__ float tile[4][16][128];
  const int b = blockIdx.x;
  const int tid = threadIdx.x;
  const int w = tid >> 6, lane = tid & 63;
  float* tw = &tile[w][0][0];
  for (int i = lane; i < 16 * 128; i += 64) tw[i] = 0.f;
  const float* hb = Hs + (size_t)b * nC * nT;
  const int tq = w * 16;
  const int tl = lane & 15;
  const int co = lane >> 4;
  for (int cb = 0; cb < nC; cb += 4) {
    const int c = cb + co;
    float v = hb[(size_t)c * nT + tq + tl];
    unsigned long long m = __ballot(v != 0.f);
    while (m) {
      const int p = __ffsll(m) - 1;
      m &= m - 1;
      const int cc = cb + (p >> 4);
      const int tt = p & 15;
      const float vv = __shfl(v, p);
      const float* er = emb + (size_t)cc * nD;
      tile[w][tt][lane]      += vv * er[lane];
      tile[w][tt][lane + 64] += vv * er[lane + 64];
    }
  }
  for (int rr = 0; rr < 16; ++rr) {
    unsigned short* o = ve + ((size_t)b * nT + tq + rr) * nD;
    o[lane]      = f2b(tile[w][rr][lane]);
    o[lane + 64] = f2b(tile[w][rr][lane + 64]);
  }
}

// ---- attention pooling ----
__global__ void k_attn(const unsigned short* __restrict__ hsb,
                       const float* __restrict__ aw,
                       unsigned short* __restrict__ hencb) {
  __shared__ float sc[nT];
  __shared__ float al[nT];
  const int b = blockIdx.x;
  const int tid = threadIdx.x;
  const int w = tid >> 6, lane = tid & 63;
  for (int t = w; t < nT; t += 4) {
    const unsigned short* hr = hsb + ((size_t)b * nT + t) * nH;
    float s = 0.f;
    for (int i = lane; i < nH; i += 64) s += b2f(hr[i]) * aw[i];
#pragma unroll
    for (int o = 32; o > 0; o >>= 1) s += __shfl_xor(s, o);
    if (lane == 0) sc[t] = s;
  }
  __syncthreads();
  if (tid < nT) {
    float v = sc[tid];
    float mx = v;
#pragma unroll
    for (int o = 32; o > 0; o >>= 1) mx = fmaxf(mx, __shfl_xor(mx, o));
    float e = expf(v - mx);
    float su = e;
#pragma unroll
    for (int o = 32; o > 0; o >>= 1) su += __shfl_xor(su, o);
    al[tid] = e / su;
  }
  __syncthreads();
  for (int col = tid; col < nH; col += 256) {
    float a = 0.f;
    for (int t = 0; t < nT; ++t) a += al[t] * b2f(hsb[((size_t)b * nT + t) * nH + col]);
    hencb[(size_t)b * nH + col] = f2b(a);
  }
}

// ---- VAE head ----
__global__ __launch_bounds__(256) void k_vae(
    const unsigned short* __restrict__ hencb,
    const unsigned short* __restrict__ Wmu, const unsigned short* __restrict__ Wvar,
    const float* __restrict__ bmu, const float* __restrict__ bvar,
    const float* __restrict__ eps,
    float* __restrict__ hf, unsigned short* __restrict__ hb,
    const int* __restrict__ lidx, float* __restrict__ out) {
  __shared__ __align__(16) unsigned short As[2 * 2048];
  __shared__ __align__(16) unsigned short Ws[2 * 2 * 2048];
  const int tid = threadIdx.x, lane = tid & 63, w = tid >> 6;
  const int mq = w & 1, nq = w >> 1;
  const int m0 = blockIdx.x * 32, n0 = blockIdx.y * 32;
  ffrag acc[2] = {};
  const unsigned short* const Wp[2] = {Wmu, Wvar};
  mm_stream<2>(acc, hencb, nH, nH, Wp, nH, m0, n0, tid, lane, mq, nq, As, Ws);
  const int col = n0 + nq * 16 + (lane & 15);
  const int rb = m0 + mq * 16 + ((lane >> 4) << 2);
#pragma unroll
  for (int i = 0; i < 4; ++i) {
    const int row = rb + i;
    const size_t idx = (size_t)row * nH + col;
    const float mu = acc[0][i] + bmu[col];
    const float lv = acc[1][i] + bvar[col];
    const float z0 = mu + expf(0.5f * lv) * eps[idx];
    hf[idx] = z0;
    hb[idx] = f2b(z0);
    if (lidx[row] == 0) out[idx] = z0;  // pred_z[b, 0]
  }
}

// ---------------------------------------------------------------------------
// Shared persistent-kernel machinery (round 8/14, proven over 864 phases):
// CP barrier (the only sync that works — sub-CP failed 3x, RMW/backoff
// variants null), XCD-local L2 data via plain-store / sc0-load, LDS W
// staging with XOR swizzle.
// ---------------------------------------------------------------------------
DEVI void rb_bar(unsigned* c, unsigned tgt) {
  asm volatile("s_waitcnt vmcnt(0)" ::: "memory");  // stores committed to L2
  __syncthreads();                                  // whole block done
  if (threadIdx.x == 0) {
    __hip_atomic_fetch_add(c, 1u, __ATOMIC_RELAXED, __HIP_MEMORY_SCOPE_AGENT);
    while (__hip_atomic_load(c, __ATOMIC_RELAXED, __HIP_MEMORY_SCOPE_AGENT) < tgt)
      __builtin_amdgcn_s_sleep(2);
  }
  __syncthreads();
}

DEVI void stageW(const unsigned short* __restrict__ Wg, int n0, int tid,
                 unsigned short* Ws) {
  const int r = tid >> 3, b0 = tid & 7;
  const unsigned short* src = Wg + (size_t)(n0 + r) * nH;
  unsigned short* dst = Ws + r * 1024;
#pragma unroll
  for (int t2 = 0; t2 < 16; ++t2) {
    const int blk = b0 + 8 * t2;
    *(uvec4*)(dst + (blk ^ (r & 7)) * 8) = *(const uvec4*)(src + blk * 8);
  }
}

// 8 A-fragments (512B along k) via sc0 loads: bypass L1, served by XCD L2.
// waitcnt is INSIDE the asm -> outputs architecturally valid at asm end.
DEVI void ld8w(uvec4 (&d)[8], const unsigned short* p) {
  asm volatile(
      "global_load_dwordx4 %0, %8, off sc0\n\t"
      "global_load_dwordx4 %1, %8, off offset:64 sc0\n\t"
      "global_load_dwordx4 %2, %8, off offset:128 sc0\n\t"
      "global_load_dwordx4 %3, %8, off offset:192 sc0\n\t"
      "global_load_dwordx4 %4, %8, off offset:256 sc0\n\t"
      "global_load_dwordx4 %5, %8, off offset:320 sc0\n\t"
      "global_load_dwordx4 %6, %8, off offset:384 sc0\n\t"
      "global_load_dwordx4 %7, %8, off offset:448 sc0\n\t"
      "s_waitcnt vmcnt(0)"
      : "=&v"(d[0]), "=&v"(d[1]), "=&v"(d[2]), "=&v"(d[3]),
        "=&v"(d[4]), "=&v"(d[5]), "=&v"(d[6]), "=&v"(d[7])
      : "v"(p)
      : "memory");
}

// 32x32x1024 tile matmul: A from XCD L2 (sc0, groups of 8), W from swizzled
// LDS, two independent accumulator chains. (proven round 8)
DEVI ffrag mm_l2(const unsigned short* ag, const unsigned short* wrow,
                 int q, int rx) {
  ffrag a0 = {0.f, 0.f, 0.f, 0.f}, a1 = {0.f, 0.f, 0.f, 0.f};
#pragma unroll
  for (int g = 0; g < 4; ++g) {
    uvec4 A[8];
    ld8w(A, ag + g * 256);
#pragma unroll
    for (int k8 = 0; k8 < 8; k8 += 2) {
      const int kk = g * 8 + k8;
      a0 = mfma16(*(const bfrag*)&A[k8],
                  *(const bfrag*)(wrow + (((kk * 4 + q) ^ rx) * 8)), a0);
      a1 = mfma16(*(const bfrag*)&A[k8 + 1],
                  *(const bfrag*)(wrow + ((((kk + 1) * 4 + q) ^ rx) * 8)), a1);
    }
  }
  return a0 + a1;
}

// Repack the wave's 16x16 C-tile through a wave-private LDS tile into
// row-contiguous 8B chunks; plain stores (write-through to XCD L2).
DEVI void pack_store(const float v[4], unsigned short* pkw, int lane,
                     unsigned short* dst /* tile base, ld=nH */) {
  const int cl = lane & 15, r0l = (lane >> 4) << 2;
#pragma unroll
  for (int i = 0; i < 4; ++i) pkw[(r0l + i) * 16 + cl] = f2b(v[i]);
  asm volatile("s_waitcnt lgkmcnt(0)" ::: "memory");  // cross-lane LDS visible
  __builtin_amdgcn_sched_barrier(0);                  // rule #18
  const int pr = lane >> 2, pc = (lane & 3) << 2;
  *(unsigned long long*)(dst + pr * nH + pc) =
      *(const unsigned long long*)(pkw + pr * 16 + pc);
}

// Same, but stores the packed value to TWO destinations (h-buffer + history).
DEVI void pack_store2(const float v[4], unsigned short* pkw, int lane,
                      unsigned short* d1 /* ld=nH */,
                      unsigned short* d2 /* ld=nT*nH */) {
  const int cl = lane & 15, r0l = (lane >> 4) << 2;
#pragma unroll
  for (int i = 0; i < 4; ++i) pkw[(r0l + i) * 16 + cl] = f2b(v[i]);
  asm volatile("s_waitcnt lgkmcnt(0)" ::: "memory");
  __builtin_amdgcn_sched_barrier(0);
  const int pr = lane >> 2, pc = (lane & 3) << 2;
  const unsigned long long val = *(const unsigned long long*)(pkw + pr * 16 + pc);
  *(unsigned long long*)(d1 + (size_t)pr * nH + pc) = val;
  *(unsigned long long*)(d2 + (size_t)pr * (nT * nH) + pc) = val;
}

// ---------------------------------------------------------------------------
// Persistent 64-step GRU (round-14 proven). Whh gate r/z slices in LDS
// (128KB), gate n from L2, Wih (3x32x128) in 24KB LDS, ve = plain cached
// loads. h double-buffered hA<->hB (sc0 read / plain write). f32 h in
// registers. ONE CP barrier per step.
// ---------------------------------------------------------------------------
__global__ __launch_bounds__(256, 1) void k_gru_persist(
    const unsigned short* __restrict__ Whh_g, const unsigned short* __restrict__ Wih_g,
    const float* __restrict__ bih, const float* __restrict__ bhh,
    const unsigned short* __restrict__ ve,
    unsigned short* hA, unsigned short* hB,
    unsigned short* hsb, unsigned* ctr) {
  __shared__ __align__(16) unsigned short Wr[32 * nH];    // 64 KB gate r
  __shared__ __align__(16) unsigned short Wz2[32 * nH];   // 64 KB gate z
  __shared__ __align__(16) unsigned short Wi[96 * nD];    // 24 KB Wih (3 gates)
  __shared__ __align__(16) unsigned short pk[4][16][16];  // 2 KB pack tiles
  __shared__ unsigned rank_sh;
  const int tid = threadIdx.x, lane = tid & 63, w = tid >> 6;
  const int mq = w & 1, nq = w >> 1;

  unsigned xcd;
  asm volatile("s_getreg_b32 %0, hwreg(HW_REG_XCC_ID)" : "=s"(xcd));
  if (tid == 0)
    rank_sh = __hip_atomic_fetch_add(ctr + 1536 + (xcd & 7) * 16, 1u,
                                     __ATOMIC_RELAXED, __HIP_MEMORY_SCOPE_AGENT);
  __syncthreads();
  const int i = (int)(xcd & 7);         // rowband == physical XCD
  const int j = (int)(rank_sh & 31);    // colblock within rowband
  const int m0 = i * 32, n0 = j * 32;

  stageW(Whh_g, n0, tid, Wr);                         // gate r
  stageW(Whh_g + (size_t)nH * nH, n0, tid, Wz2);      // gate z
  for (int idx = tid; idx < 96 * 16; idx += 256) {    // Wih, 3 gates x 32 rows
    const int r = idx >> 4, blk = idx & 15;
    const int gate = r >> 5, rr2 = r & 31;
    *(uvec4*)(Wi + r * nD + ((blk ^ (r & 7)) * 8)) =
        *(const uvec4*)(Wih_g + ((size_t)gate * nH + n0 + rr2) * nD + blk * 8);
  }

  const int col = n0 + nq * 16 + (lane & 15);
  const int arow = m0 + mq * 16 + (lane & 15);
  const int q = lane >> 4;
  const int rw = nq * 16 + (lane & 15);
  const int rx = rw & 7;
  const unsigned short* wrr = Wr + rw * nH;
  const unsigned short* wzr = Wz2 + rw * nH;
  const unsigned short* wir = Wi + rw * nD;
  const unsigned short* wiz = Wi + (32 + rw) * nD;
  const unsigned short* win = Wi + (64 + rw) * nD;
  const unsigned short* wng = Whh_g + ((size_t)2 * nH + col) * nH + q * 8;  // gate n, L2
  const unsigned short* aA = hA + (size_t)arow * nH + q * 8;
  const unsigned short* aB = hB + (size_t)arow * nH + q * 8;
  unsigned short* dA = hA + (size_t)(m0 + mq * 16) * nH + n0 + nq * 16;
  unsigned short* dB = hB + (size_t)(m0 + mq * 16) * nH + n0 + nq * 16;
  unsigned short* dh = hsb + (size_t)(m0 + mq * 16) * nT * nH + n0 + nq * 16;
  unsigned short* pkw = &pk[w][0][0];
  const float b_r = bih[col] + bhh[col];
  const float b_z = bih[nH + col] + bhh[nH + col];
  const float bi_n = bih[2 * nH + col];
  const float bh_n = bhh[2 * nH + col];

  float hf_[4] = {0.f, 0.f, 0.f, 0.f};   // f32 h state (h0 = 0)
  unsigned* myc = ctr + 1024 + i * 64;   // GRU barrier counters (own region)
  unsigned ph = 0;
  __syncthreads();   // weights staged

#pragma unroll 1
  for (int t = 0; t < nT; ++t) {
    const unsigned short* ah = (t & 1) ? aB : aA;   // read buffer
    unsigned short* dst = (t & 1) ? dA : dB;        // write buffer
    ffrag ar = {0.f, 0.f, 0.f, 0.f}, az = {0.f, 0.f, 0.f, 0.f},
          an = {0.f, 0.f, 0.f, 0.f};
#pragma unroll
    for (int g = 0; g < 4; ++g) {
      uvec4 A[8];
      ld8w(A, ah + g * 256);
#pragma unroll
      for (int k8 = 0; k8 < 8; ++k8) {
        const int kk = g * 8 + k8;
        const int wo = ((kk * 4 + q) ^ rx) * 8;
        const bfrag af = *(const bfrag*)&A[k8];
        ar = mfma16(af, *(const bfrag*)(wrr + wo), ar);
        az = mfma16(af, *(const bfrag*)(wzr + wo), az);
        an = mfma16(af, *(const bfrag*)(wng + kk * 32), an);
      }
    }
    ffrag ir = {0.f, 0.f, 0.f, 0.f}, iz = {0.f, 0.f, 0.f, 0.f},
          in_ = {0.f, 0.f, 0.f, 0.f};
    const unsigned short* av = ve + ((size_t)arow * nT + t) * nD + q * 8;
#pragma unroll
    for (int kk = 0; kk < 4; ++kk) {
      const bfrag af = *(const bfrag*)(av + kk * 32);
      const int wo = ((kk * 4 + q) ^ rx) * 8;
      ir = mfma16(af, *(const bfrag*)(wir + wo), ir);
      iz = mfma16(af, *(const bfrag*)(wiz + wo), iz);
      in_ = mfma16(af, *(const bfrag*)(win + wo), in_);
    }
    float hv[4];
#pragma unroll
    for (int ii = 0; ii < 4; ++ii) {
      const float rr2 = sigm(ar[ii] + ir[ii] + b_r);
      const float zv = sigm(az[ii] + iz[ii] + b_z);
      const float nn = tanhf(in_[ii] + bi_n + rr2 * (an[ii] + bh_n));
      const float hn2 = (1.f - zv) * nn + zv * hf_[ii];
      hf_[ii] = hn2;
      hv[ii] = hn2;
    }
    pack_store2(hv, pkw, lane, dst, dh + (size_t)t * nH);
    ph += 32; rb_bar(myc, ph);
  }
}

// ---------------------------------------------------------------------------
// Persistent GRU-ODE RK4 integrator — round 8/14 structure (proven best).
// ---------------------------------------------------------------------------
__global__ __launch_bounds__(256, 1) void k_ode_persist(
    const unsigned short* __restrict__ Wz_g, const unsigned short* __restrict__ Wn_g,
    const float* __restrict__ h0f, unsigned short* xb, unsigned short* gbuf,
    const float* __restrict__ ts, const int* __restrict__ lidx,
    float* __restrict__ out, unsigned* ctr) {
  __shared__ __align__(16) unsigned short Wz[32 * nH];     // 64 KB
  __shared__ __align__(16) unsigned short Wn[32 * nH];     // 64 KB
  __shared__ __align__(16) unsigned short pk[4][16][16];   // 2 KB pack tiles
  __shared__ unsigned rank_sh;
  const int tid = threadIdx.x, lane = tid & 63, w = tid >> 6;
  const int mq = w & 1, nq = w >> 1;

  unsigned xcd;
  asm volatile("s_getreg_b32 %0, hwreg(HW_REG_XCC_ID)" : "=s"(xcd));
  if (tid == 0)
    rank_sh = __hip_atomic_fetch_add(ctr + 512 + (xcd & 7) * 16, 1u,
                                     __ATOMIC_RELAXED, __HIP_MEMORY_SCOPE_AGENT);
  __syncthreads();
  const int i = (int)(xcd & 7);         // rowband == physical XCD
  const int j = (int)(rank_sh & 31);    // colblock within rowband
  const int m0 = i * 32, n0 = j * 32;

  stageW(Wz_g, n0, tid, Wz);
  stageW(Wn_g, n0, tid, Wn);

  const int col = n0 + nq * 16 + (lane & 15);            // owned output col
  const int row0 = m0 + mq * 16 + ((lane >> 4) << 2);    // owned output rows
  const int arow = m0 + mq * 16 + (lane & 15);           // A-frag row
  const int q = lane >> 4;
  const int rw = nq * 16 + (lane & 15);                  // W row read by lane
  const int rx = rw & 7;
  const unsigned short* wzrow = Wz + rw * nH;
  const unsigned short* wnrow = Wn + rw * nH;
  const unsigned short* axb = xb + (size_t)arow * nH + q * 8;
  const unsigned short* agb = gbuf + (size_t)arow * nH + q * 8;
  unsigned short* pkw = &pk[w][0][0];
  unsigned short* gdst = gbuf + (size_t)(m0 + mq * 16) * nH + n0 + nq * 16;
  unsigned short* xdst = xb + (size_t)(m0 + mq * 16) * nH + n0 + nq * 16;

  float hb[4], xv[4], ka[4];
  int lst[4];
#pragma unroll
  for (int ii = 0; ii < 4; ++ii) {
    hb[ii] = h0f[(size_t)(row0 + ii) * nH + col];
    xv[ii] = hb[ii];
    lst[ii] = lidx[row0 + ii];
  }
  unsigned* myc = ctr + i * 64;   // 256B-padded per-rowband barrier counter
  unsigned ph = 0;
  __syncthreads();   // weights staged

  for (int s = 0; s < nNT - 1; ++s) {
    const float dt = ts[s + 1] - ts[s];
#pragma unroll 1
    for (int stg = 0; stg < 4; ++stg) {
      // ---- mm1: zz = sigmoid(x @ Whz^T); g = zz * x ----
      ffrag acc = mm_l2(axb, wzrow, q, rx);
      float zv[4], gv[4];
#pragma unroll
      for (int ii = 0; ii < 4; ++ii) {
        zv[ii] = sigm(acc[ii]);
        gv[ii] = zv[ii] * xv[ii];
      }
      pack_store(gv, pkw, lane, gdst);
      ph += 32; rb_bar(myc, ph);
      // ---- mm2: nn = tanh(g @ Whn^T); f = (1-zz)*(nn-x); stage update ----
      acc = mm_l2(agb, wnrow, q, rx);
#pragma unroll
      for (int ii = 0; ii < 4; ++ii) {
        const float nn = tanhf(acc[ii]);
        const float fv = (1.f - zv[ii]) * (nn - xv[ii]);
        if (stg == 0)      { ka[ii] = fv;        xv[ii] = hb[ii] + 0.5f * dt * fv; }
        else if (stg == 1) { ka[ii] += 2.f * fv; xv[ii] = hb[ii] + 0.5f * dt * fv; }
        else if (stg == 2) { ka[ii] += 2.f * fv; xv[ii] = hb[ii] + dt * fv; }
        else {
          const float hn = hb[ii] + (dt * (1.f / 6.f)) * (ka[ii] + fv);
          hb[ii] = hn; xv[ii] = hn;
          if (lst[ii] == s + 1) out[(size_t)(row0 + ii) * nH + col] = hn;
        }
      }
      pack_store(xv, pkw, lane, xdst);
      ph += 32; rb_bar(myc, ph);
    }
  }
}

}  // namespace

extern "C" void kernel_launch(void* const* d_in, const int* in_sizes, int n_in,
                              void* d_out, int out_size, void* d_ws, size_t ws_size,
                              hipStream_t stream) {
  const float* Hs   = (const float*)d_in[0];
  const float* ts   = (const float*)d_in[1];
  const int*   lidx = (const int*)d_in[2];
  const int*   llm  = (const int*)d_in[3];
  const float* eps  = (const float*)d_in[4];
  const float* emb  = (const float*)d_in[5];
  const float* Wih  = (const float*)d_in[6];
  const float* Whh  = (const float*)d_in[7];
  const float* bih  = (const float*)d_in[8];
  const float* bhh  = (const float*)d_in[9];
  const float* aw   = (const float*)d_in[10];
  const float* Wmu  = (const float*)d_in[11];
  const float* bmu  = (const float*)d_in[12];
  const float* Wvar = (const float*)d_in[13];
  const float* bvar = (const float*)d_in[14];
  const float* Whz  = (const float*)d_in[15];
  const float* Whn  = (const float*)d_in[16];

  float* out_last = (float*)d_out;
  float* out_mask = out_last + (size_t)nB * nH;

  char* p = (char*)d_ws;
  auto alloc = [&](size_t bytes) {
    void* r = p; p += (bytes + 255) & ~(size_t)255; return r;
  };
  unsigned short* Whh_b  = (unsigned short*)alloc((size_t)3 * nH * nH * 2);
  unsigned short* Wih_b  = (unsigned short*)alloc((size_t)3 * nH * nD * 2);
  unsigned short* Wmu_b  = (unsigned short*)alloc((size_t)nH * nH * 2);
  unsigned short* Wvar_b = (unsigned short*)alloc((size_t)nH * nH * 2);
  unsigned short* Whz_b  = (unsigned short*)alloc((size_t)nH * nH * 2);
  unsigned short* Whn_b  = (unsigned short*)alloc((size_t)nH * nH * 2);
  unsigned short* ve_b   = (unsigned short*)alloc((size_t)nB * nT * nD * 2);
  unsigned short* hs_b   = (unsigned short*)alloc((size_t)nB * nT * nH * 2);
  float* h0f             = (float*)alloc((size_t)nB * nH * 4);
  unsigned short* h0b    = (unsigned short*)alloc((size_t)nB * nH * 2);
  unsigned short* h1b    = (unsigned short*)alloc((size_t)nB * nH * 2);
  unsigned short* gb     = (unsigned short*)alloc((size_t)nB * nH * 2);
  unsigned short* hencb  = (unsigned short*)alloc((size_t)nB * nH * 2);
  unsigned* ctr          = (unsigned*)alloc(8192);   // barriers + rank ctrs

  hipMemsetAsync(h0b, 0, (size_t)nB * nH * 2, stream);   // GRU h0 = 0
  hipMemsetAsync(ctr, 0, 8192, stream);                  // all counters

  auto cvt = [&](const float* s, unsigned short* d, int n) {
    k_cvt<<<n / 1024, 256, 0, stream>>>(s, d, n);
  };
  cvt(Whh, Whh_b, 3 * nH * nH);
  cvt(Wih, Wih_b, 3 * nH * nD);
  cvt(Wmu, Wmu_b, nH * nH);
  cvt(Wvar, Wvar_b, nH * nH);
  cvt(Whz, Whz_b, nH * nH);
  cvt(Whn, Whn_b, nH * nH);

  k_embed<<<nB, 256, 0, stream>>>(Hs, emb, ve_b);
  k_mask<<<dim3((nC + 255) / 256, nB), 256, 0, stream>>>(llm, out_mask);

  // entire 64-step GRU in one persistent kernel (1 CP barrier per step)
  k_gru_persist<<<256, 256, 0, stream>>>(Whh_b, Wih_b, bih, bhh, ve_b,
                                         h0b, h1b, hs_b, ctr);

  k_attn<<<nB, 256, 0, stream>>>(hs_b, aw, hencb);
  const dim3 gg(nB / 32, nH / 32);  // 8 x 32 = 256 blocks
  // z0 -> h0f (f32 base state) + h0b (bf16, first mm1 A-operand)
  k_vae<<<gg, 256, 0, stream>>>(hencb, Wmu_b, Wvar_b, bmu, bvar, eps,
                                h0f, h0b, lidx, out_last);

  // entire 100-step RK4 GRU-ODE in one persistent kernel (round 8/14 proven)
  k_ode_persist<<<256, 256, 0, stream>>>(Whz_b, Whn_b, h0f, h0b, gb, ts, lidx,
                                         out_last, ctr);
}

// Round 19
// 4979.736 us; speedup vs baseline: 1.2631x; 1.0835x over previous
//
#include <hip/hip_runtime.h>
#include <hip/hip_bf16.h>

#define DEVI __device__ __forceinline__

namespace {

constexpr int nB = 256, nT = 64, nC = 4880, nD = 128, nH = 1024, nNT = 101, nND = 10;

typedef __attribute__((ext_vector_type(8))) short bfrag;   // 8 bf16 = 4 VGPR (MFMA A/B)
typedef __attribute__((ext_vector_type(4))) float ffrag;   // MFMA C/D
typedef __attribute__((ext_vector_type(4))) unsigned int uvec4;

DEVI ffrag mfma16(bfrag a, bfrag b, ffrag c) {
  return __builtin_amdgcn_mfma_f32_16x16x32_bf16(a, b, c, 0, 0, 0);
}

DEVI unsigned short f2b(float x) {
  __hip_bfloat16 h = __float2bfloat16(x);
  return *reinterpret_cast<unsigned short*>(&h);
}
DEVI float b2f(unsigned short u) {
  __hip_bfloat16 h;
  *reinterpret_cast<unsigned short*>(&h) = u;
  return __bfloat162float(h);
}
DEVI float sigm(float x) { return 1.f / (1.f + expf(-x)); }

// ---------------------------------------------------------------------------
// Double-buffered bf16 MFMA tile stream (VAE kernel — proven path).
// ---------------------------------------------------------------------------
template<int NS>
DEVI void mm_stream(ffrag (&acc)[NS],
                    const unsigned short* __restrict__ A, int lda, int K,
                    const unsigned short* const (&Wp)[NS], int ldw,
                    int m0, int n0, int tid, int lane, int mq, int nq,
                    unsigned short* As, unsigned short* Ws) {
  const int r = tid >> 3, blk = tid & 7;
  const int wrOff = (r * 8 + (blk ^ (r & 7))) * 8;   // ushort offset
  const int ra = mq * 16 + (lane & 15);              // A-frag row (m)
  const int rw = nq * 16 + (lane & 15);              // W-frag row (n)
  const int q = lane >> 4;                           // k-quadrant
  const int nc = K >> 6;                             // 64-wide K chunks

  uvec4 va = *(const uvec4*)(A + (size_t)(m0 + r) * lda + blk * 8);
  uvec4 vw[NS];
#pragma unroll
  for (int s = 0; s < NS; ++s)
    vw[s] = *(const uvec4*)(Wp[s] + (size_t)(n0 + r) * ldw + blk * 8);
  *(uvec4*)(As + wrOff) = va;
#pragma unroll
  for (int s = 0; s < NS; ++s) *(uvec4*)(Ws + s * 2048 + wrOff) = vw[s];

  for (int ci = 0; ci < nc; ++ci) {
    __syncthreads();
    const int cur = ci & 1;
    const bool more = (ci + 1) < nc;
    if (more) {
      const int k0 = (ci + 1) << 6;
      va = *(const uvec4*)(A + (size_t)(m0 + r) * lda + k0 + blk * 8);
#pragma unroll
      for (int s = 0; s < NS; ++s)
        vw[s] = *(const uvec4*)(Wp[s] + (size_t)(n0 + r) * ldw + k0 + blk * 8);
    }
    const unsigned short* Ab = As + cur * 2048;
    const unsigned short* Wb = Ws + cur * (NS * 2048);
#pragma unroll
    for (int kk = 0; kk < 2; ++kk) {
      bfrag af = *(const bfrag*)(Ab + (ra * 8 + ((kk * 4 + q) ^ (ra & 7))) * 8);
#pragma unroll
      for (int s = 0; s < NS; ++s) {
        bfrag wf = *(const bfrag*)(Wb + s * 2048 + (rw * 8 + ((kk * 4 + q) ^ (rw & 7))) * 8);
        acc[s] = mfma16(af, wf, acc[s]);
      }
    }
    if (more) {
      const int nx = cur ^ 1;
      *(uvec4*)(As + nx * 2048 + wrOff) = va;
#pragma unroll
      for (int s = 0; s < NS; ++s)
        *(uvec4*)(Ws + nx * (NS * 2048) + s * 2048 + wrOff) = vw[s];
    }
  }
  __syncthreads();
}

// ---- fp32 -> bf16 bulk convert (n divisible by 1024) ----
__global__ void k_cvt(const float* __restrict__ s, unsigned short* __restrict__ d, int n) {
  int i = blockIdx.x * blockDim.x + threadIdx.x;
  float4 v = ((const float4*)s)[i];
  unsigned int u0 = (unsigned int)f2b(v.x) | ((unsigned int)f2b(v.y) << 16);
  unsigned int u1 = (unsigned int)f2b(v.z) | ((unsigned int)f2b(v.w) << 16);
  ((uint2*)d)[i] = make_uint2(u0, u1);
}

// ---- LLM diagnosis mask ----
__global__ void k_mask(const int* __restrict__ llm, float* __restrict__ outm) {
  int c = blockIdx.x * 256 + threadIdx.x;
  int b = blockIdx.y;
  if (c >= nC) return;
  const int* lr = llm + b * nND;
  float v = 0.f;
#pragma unroll
  for (int i = 0; i < nND; ++i) v = (lr[i] == c) ? 1.f : v;
  outm[(size_t)b * nC + c] = v;
}

// ---- sparse visit embedding (x16-unrolled scan: 16 HBM loads in flight) ----
// Round 18's scan was a 1220-iteration serial load->ballot chain per wave
// (~0.5-0.9us HBM latency each == the hidden ~0.6-0.9ms). Now 16 independent
// bounds-checked loads issue before any ballot processing; iteration count
// drops to 77. Accumulation order (c ascending, lane order within ballot)
// is IDENTICAL -> bit-identical output.
__global__ void k_embed(const float* __restrict__ Hs, const float* __restrict__ emb,
                        unsigned short* __restrict__ ve) {
  __shared__ float tile[4][16][128];
  const int b = blockIdx.x;
  const int tid = threadIdx.x;
  const int w = tid >> 6, lane = tid & 63;
  float* tw = &tile[w][0][0];
  for (int i = lane; i < 16 * 128; i += 64) tw[i] = 0.f;
  const float* hb = Hs + (size_t)b * nC * nT;
  const int tq = w * 16;
  const int tl = lane & 15;
  const int co = lane >> 4;
  for (int cb = 0; cb < nC; cb += 64) {   // 16 groups of 4 c's per iteration
    float v[16];
#pragma unroll
    for (int u = 0; u < 16; ++u) {
      const int c = cb + u * 4 + co;
      v[u] = (c < nC) ? hb[(size_t)c * nT + tq + tl] : 0.f;
    }
#pragma unroll
    for (int u = 0; u < 16; ++u) {
      unsigned long long m = __ballot(v[u] != 0.f);
      while (m) {
        const int p = __ffsll(m) - 1;
        m &= m - 1;
        const int cc = cb + u * 4 + (p >> 4);
        const int tt = p & 15;
        const float vv = __shfl(v[u], p);
        const float* er = emb + (size_t)cc * nD;
        tile[w][tt][lane]      += vv * er[lane];
        tile[w][tt][lane + 64] += vv * er[lane + 64];
      }
    }
  }
  for (int rr = 0; rr < 16; ++rr) {
    unsigned short* o = ve + ((size_t)b * nT + tq + rr) * nD;
    o[lane]      = f2b(tile[w][rr][lane]);
    o[lane + 64] = f2b(tile[w][rr][lane + 64]);
  }
}

// ---- attention pooling ----
__global__ void k_attn(const unsigned short* __restrict__ hsb,
                       const float* __restrict__ aw,
                       unsigned short* __restrict__ hencb) {
  __shared__ float sc[nT];
  __shared__ float al[nT];
  const int b = blockIdx.x;
  const int tid = threadIdx.x;
  const int w = tid >> 6, lane = tid & 63;
  for (int t = w; t < nT; t += 4) {
    const unsigned short* hr = hsb + ((size_t)b * nT + t) * nH;
    float s = 0.f;
    for (int i = lane; i < nH; i += 64) s += b2f(hr[i]) * aw[i];
#pragma unroll
    for (int o = 32; o > 0; o >>= 1) s += __shfl_xor(s, o);
    if (lane == 0) sc[t] = s;
  }
  __syncthreads();
  if (tid < nT) {
    float v = sc[tid];
    float mx = v;
#pragma unroll
    for (int o = 32; o > 0; o >>= 1) mx = fmaxf(mx, __shfl_xor(mx, o));
    float e = expf(v - mx);
    float su = e;
#pragma unroll
    for (int o = 32; o > 0; o >>= 1) su += __shfl_xor(su, o);
    al[tid] = e / su;
  }
  __syncthreads();
  for (int col = tid; col < nH; col += 256) {
    float a = 0.f;
    for (int t = 0; t < nT; ++t) a += al[t] * b2f(hsb[((size_t)b * nT + t) * nH + col]);
    hencb[(size_t)b * nH + col] = f2b(a);
  }
}

// ---- VAE head ----
__global__ __launch_bounds__(256) void k_vae(
    const unsigned short* __restrict__ hencb,
    const unsigned short* __restrict__ Wmu, const unsigned short* __restrict__ Wvar,
    const float* __restrict__ bmu, const float* __restrict__ bvar,
    const float* __restrict__ eps,
    float* __restrict__ hf, unsigned short* __restrict__ hb,
    const int* __restrict__ lidx, float* __restrict__ out) {
  __shared__ __align__(16) unsigned short As[2 * 2048];
  __shared__ __align__(16) unsigned short Ws[2 * 2 * 2048];
  const int tid = threadIdx.x, lane = tid & 63, w = tid >> 6;
  const int mq = w & 1, nq = w >> 1;
  const int m0 = blockIdx.x * 32, n0 = blockIdx.y * 32;
  ffrag acc[2] = {};
  const unsigned short* const Wp[2] = {Wmu, Wvar};
  mm_stream<2>(acc, hencb, nH, nH, Wp, nH, m0, n0, tid, lane, mq, nq, As, Ws);
  const int col = n0 + nq * 16 + (lane & 15);
  const int rb = m0 + mq * 16 + ((lane >> 4) << 2);
#pragma unroll
  for (int i = 0; i < 4; ++i) {
    const int row = rb + i;
    const size_t idx = (size_t)row * nH + col;
    const float mu = acc[0][i] + bmu[col];
    const float lv = acc[1][i] + bvar[col];
    const float z0 = mu + expf(0.5f * lv) * eps[idx];
    hf[idx] = z0;
    hb[idx] = f2b(z0);
    if (lidx[row] == 0) out[idx] = z0;  // pred_z[b, 0]
  }
}

// ---------------------------------------------------------------------------
// Shared persistent-kernel machinery (round 8/14, proven over 864 phases).
// ---------------------------------------------------------------------------
DEVI void rb_bar(unsigned* c, unsigned tgt) {
  asm volatile("s_waitcnt vmcnt(0)" ::: "memory");  // stores committed to L2
  __syncthreads();                                  // whole block done
  if (threadIdx.x == 0) {
    __hip_atomic_fetch_add(c, 1u, __ATOMIC_RELAXED, __HIP_MEMORY_SCOPE_AGENT);
    while (__hip_atomic_load(c, __ATOMIC_RELAXED, __HIP_MEMORY_SCOPE_AGENT) < tgt)
      __builtin_amdgcn_s_sleep(2);
  }
  __syncthreads();
}

DEVI void stageW(const unsigned short* __restrict__ Wg, int n0, int tid,
                 unsigned short* Ws) {
  const int r = tid >> 3, b0 = tid & 7;
  const unsigned short* src = Wg + (size_t)(n0 + r) * nH;
  unsigned short* dst = Ws + r * 1024;
#pragma unroll
  for (int t2 = 0; t2 < 16; ++t2) {
    const int blk = b0 + 8 * t2;
    *(uvec4*)(dst + (blk ^ (r & 7)) * 8) = *(const uvec4*)(src + blk * 8);
  }
}

// 8 A-fragments (512B along k) via sc0 loads: bypass L1, served by XCD L2.
// waitcnt is INSIDE the asm -> outputs architecturally valid at asm end.
DEVI void ld8w(uvec4 (&d)[8], const unsigned short* p) {
  asm volatile(
      "global_load_dwordx4 %0, %8, off sc0\n\t"
      "global_load_dwordx4 %1, %8, off offset:64 sc0\n\t"
      "global_load_dwordx4 %2, %8, off offset:128 sc0\n\t"
      "global_load_dwordx4 %3, %8, off offset:192 sc0\n\t"
      "global_load_dwordx4 %4, %8, off offset:256 sc0\n\t"
      "global_load_dwordx4 %5, %8, off offset:320 sc0\n\t"
      "global_load_dwordx4 %6, %8, off offset:384 sc0\n\t"
      "global_load_dwordx4 %7, %8, off offset:448 sc0\n\t"
      "s_waitcnt vmcnt(0)"
      : "=&v"(d[0]), "=&v"(d[1]), "=&v"(d[2]), "=&v"(d[3]),
        "=&v"(d[4]), "=&v"(d[5]), "=&v"(d[6]), "=&v"(d[7])
      : "v"(p)
      : "memory");
}

// 32x32x1024 tile matmul: A from XCD L2 (sc0, groups of 8), W from swizzled
// LDS, two independent accumulator chains. (proven round 8)
DEVI ffrag mm_l2(const unsigned short* ag, const unsigned short* wrow,
                 int q, int rx) {
  ffrag a0 = {0.f, 0.f, 0.f, 0.f}, a1 = {0.f, 0.f, 0.f, 0.f};
#pragma unroll
  for (int g = 0; g < 4; ++g) {
    uvec4 A[8];
    ld8w(A, ag + g * 256);
#pragma unroll
    for (int k8 = 0; k8 < 8; k8 += 2) {
      const int kk = g * 8 + k8;
      a0 = mfma16(*(const bfrag*)&A[k8],
                  *(const bfrag*)(wrow + (((kk * 4 + q) ^ rx) * 8)), a0);
      a1 = mfma16(*(const bfrag*)&A[k8 + 1],
                  *(const bfrag*)(wrow + ((((kk + 1) * 4 + q) ^ rx) * 8)), a1);
    }
  }
  return a0 + a1;
}

// Repack the wave's 16x16 C-tile through a wave-private LDS tile into
// row-contiguous 8B chunks; plain stores (write-through to XCD L2).
DEVI void pack_store(const float v[4], unsigned short* pkw, int lane,
                     unsigned short* dst /* tile base, ld=nH */) {
  const int cl = lane & 15, r0l = (lane >> 4) << 2;
#pragma unroll
  for (int i = 0; i < 4; ++i) pkw[(r0l + i) * 16 + cl] = f2b(v[i]);
  asm volatile("s_waitcnt lgkmcnt(0)" ::: "memory");  // cross-lane LDS visible
  __builtin_amdgcn_sched_barrier(0);                  // rule #18
  const int pr = lane >> 2, pc = (lane & 3) << 2;
  *(unsigned long long*)(dst + pr * nH + pc) =
      *(const unsigned long long*)(pkw + pr * 16 + pc);
}

// Same, but stores the packed value to TWO destinations (h-buffer + history).
DEVI void pack_store2(const float v[4], unsigned short* pkw, int lane,
                      unsigned short* d1 /* ld=nH */,
                      unsigned short* d2 /* ld=nT*nH */) {
  const int cl = lane & 15, r0l = (lane >> 4) << 2;
#pragma unroll
  for (int i = 0; i < 4; ++i) pkw[(r0l + i) * 16 + cl] = f2b(v[i]);
  asm volatile("s_waitcnt lgkmcnt(0)" ::: "memory");
  __builtin_amdgcn_sched_barrier(0);
  const int pr = lane >> 2, pc = (lane & 3) << 2;
  const unsigned long long val = *(const unsigned long long*)(pkw + pr * 16 + pc);
  *(unsigned long long*)(d1 + (size_t)pr * nH + pc) = val;
  *(unsigned long long*)(d2 + (size_t)pr * (nT * nH) + pc) = val;
}

// ---------------------------------------------------------------------------
// Persistent 64-step GRU (round-14 proven).
// ---------------------------------------------------------------------------
__global__ __launch_bounds__(256, 1) void k_gru_persist(
    const unsigned short* __restrict__ Whh_g, const unsigned short* __restrict__ Wih_g,
    const float* __restrict__ bih, const float* __restrict__ bhh,
    const unsigned short* __restrict__ ve,
    unsigned short* hA, unsigned short* hB,
    unsigned short* hsb, unsigned* ctr) {
  __shared__ __align__(16) unsigned short Wr[32 * nH];    // 64 KB gate r
  __shared__ __align__(16) unsigned short Wz2[32 * nH];   // 64 KB gate z
  __shared__ __align__(16) unsigned short Wi[96 * nD];    // 24 KB Wih (3 gates)
  __shared__ __align__(16) unsigned short pk[4][16][16];  // 2 KB pack tiles
  __shared__ unsigned rank_sh;
  const int tid = threadIdx.x, lane = tid & 63, w = tid >> 6;
  const int mq = w & 1, nq = w >> 1;

  unsigned xcd;
  asm volatile("s_getreg_b32 %0, hwreg(HW_REG_XCC_ID)" : "=s"(xcd));
  if (tid == 0)
    rank_sh = __hip_atomic_fetch_add(ctr + 1536 + (xcd & 7) * 16, 1u,
                                     __ATOMIC_RELAXED, __HIP_MEMORY_SCOPE_AGENT);
  __syncthreads();
  const int i = (int)(xcd & 7);         // rowband == physical XCD
  const int j = (int)(rank_sh & 31);    // colblock within rowband
  const int m0 = i * 32, n0 = j * 32;

  stageW(Whh_g, n0, tid, Wr);                         // gate r
  stageW(Whh_g + (size_t)nH * nH, n0, tid, Wz2);      // gate z
  for (int idx = tid; idx < 96 * 16; idx += 256) {    // Wih, 3 gates x 32 rows
    const int r = idx >> 4, blk = idx & 15;
    const int gate = r >> 5, rr2 = r & 31;
    *(uvec4*)(Wi + r * nD + ((blk ^ (r & 7)) * 8)) =
        *(const uvec4*)(Wih_g + ((size_t)gate * nH + n0 + rr2) * nD + blk * 8);
  }

  const int col = n0 + nq * 16 + (lane & 15);
  const int arow = m0 + mq * 16 + (lane & 15);
  const int q = lane >> 4;
  const int rw = nq * 16 + (lane & 15);
  const int rx = rw & 7;
  const unsigned short* wrr = Wr + rw * nH;
  const unsigned short* wzr = Wz2 + rw * nH;
  const unsigned short* wir = Wi + rw * nD;
  const unsigned short* wiz = Wi + (32 + rw) * nD;
  const unsigned short* win = Wi + (64 + rw) * nD;
  const unsigned short* wng = Whh_g + ((size_t)2 * nH + col) * nH + q * 8;  // gate n, L2
  const unsigned short* aA = hA + (size_t)arow * nH + q * 8;
  const unsigned short* aB = hB + (size_t)arow * nH + q * 8;
  unsigned short* dA = hA + (size_t)(m0 + mq * 16) * nH + n0 + nq * 16;
  unsigned short* dB = hB + (size_t)(m0 + mq * 16) * nH + n0 + nq * 16;
  unsigned short* dh = hsb + (size_t)(m0 + mq * 16) * nT * nH + n0 + nq * 16;
  unsigned short* pkw = &pk[w][0][0];
  const float b_r = bih[col] + bhh[col];
  const float b_z = bih[nH + col] + bhh[nH + col];
  const float bi_n = bih[2 * nH + col];
  const float bh_n = bhh[2 * nH + col];

  float hf_[4] = {0.f, 0.f, 0.f, 0.f};   // f32 h state (h0 = 0)
  unsigned* myc = ctr + 1024 + i * 64;   // GRU barrier counters (own region)
  unsigned ph = 0;
  __syncthreads();   // weights staged

#pragma unroll 1
  for (int t = 0; t < nT; ++t) {
    const unsigned short* ah = (t & 1) ? aB : aA;   // read buffer
    unsigned short* dst = (t & 1) ? dA : dB;        // write buffer
    ffrag ar = {0.f, 0.f, 0.f, 0.f}, az = {0.f, 0.f, 0.f, 0.f},
          an = {0.f, 0.f, 0.f, 0.f};
#pragma unroll
    for (int g = 0; g < 4; ++g) {
      uvec4 A[8];
      ld8w(A, ah + g * 256);
#pragma unroll
      for (int k8 = 0; k8 < 8; ++k8) {
        const int kk = g * 8 + k8;
        const int wo = ((kk * 4 + q) ^ rx) * 8;
        const bfrag af = *(const bfrag*)&A[k8];
        ar = mfma16(af, *(const bfrag*)(wrr + wo), ar);
        az = mfma16(af, *(const bfrag*)(wzr + wo), az);
        an = mfma16(af, *(const bfrag*)(wng + kk * 32), an);
      }
    }
    ffrag ir = {0.f, 0.f, 0.f, 0.f}, iz = {0.f, 0.f, 0.f, 0.f},
          in_ = {0.f, 0.f, 0.f, 0.f};
    const unsigned short* av = ve + ((size_t)arow * nT + t) * nD + q * 8;
#pragma unroll
    for (int kk = 0; kk < 4; ++kk) {
      const bfrag af = *(const bfrag*)(av + kk * 32);
      const int wo = ((kk * 4 + q) ^ rx) * 8;
      ir = mfma16(af, *(const bfrag*)(wir + wo), ir);
      iz = mfma16(af, *(const bfrag*)(wiz + wo), iz);
      in_ = mfma16(af, *(const bfrag*)(win + wo), in_);
    }
    float hv[4];
#pragma unroll
    for (int ii = 0; ii < 4; ++ii) {
      const float rr2 = sigm(ar[ii] + ir[ii] + b_r);
      const float zv = sigm(az[ii] + iz[ii] + b_z);
      const float nn = tanhf(in_[ii] + bi_n + rr2 * (an[ii] + bh_n));
      const float hn2 = (1.f - zv) * nn + zv * hf_[ii];
      hf_[ii] = hn2;
      hv[ii] = hn2;
    }
    pack_store2(hv, pkw, lane, dst, dh + (size_t)t * nH);
    ph += 32; rb_bar(myc, ph);
  }
}

// ---------------------------------------------------------------------------
// Persistent GRU-ODE RK4 integrator — round 8/14 structure (proven best).
// ---------------------------------------------------------------------------
__global__ __launch_bounds__(256, 1) void k_ode_persist(
    const unsigned short* __restrict__ Wz_g, const unsigned short* __restrict__ Wn_g,
    const float* __restrict__ h0f, unsigned short* xb, unsigned short* gbuf,
    const float* __restrict__ ts, const int* __restrict__ lidx,
    float* __restrict__ out, unsigned* ctr) {
  __shared__ __align__(16) unsigned short Wz[32 * nH];     // 64 KB
  __shared__ __align__(16) unsigned short Wn[32 * nH];     // 64 KB
  __shared__ __align__(16) unsigned short pk[4][16][16];   // 2 KB pack tiles
  __shared__ unsigned rank_sh;
  const int tid = threadIdx.x, lane = tid & 63, w = tid >> 6;
  const int mq = w & 1, nq = w >> 1;

  unsigned xcd;
  asm volatile("s_getreg_b32 %0, hwreg(HW_REG_XCC_ID)" : "=s"(xcd));
  if (tid == 0)
    rank_sh = __hip_atomic_fetch_add(ctr + 512 + (xcd & 7) * 16, 1u,
                                     __ATOMIC_RELAXED, __HIP_MEMORY_SCOPE_AGENT);
  __syncthreads();
  const int i = (int)(xcd & 7);         // rowband == physical XCD
  const int j = (int)(rank_sh & 31);    // colblock within rowband
  const int m0 = i * 32, n0 = j * 32;

  stageW(Wz_g, n0, tid, Wz);
  stageW(Wn_g, n0, tid, Wn);

  const int col = n0 + nq * 16 + (lane & 15);            // owned output col
  const int row0 = m0 + mq * 16 + ((lane >> 4) << 2);    // owned output rows
  const int arow = m0 + mq * 16 + (lane & 15);           // A-frag row
  const int q = lane >> 4;
  const int rw = nq * 16 + (lane & 15);                  // W row read by lane
  const int rx = rw & 7;
  const unsigned short* wzrow = Wz + rw * nH;
  const unsigned short* wnrow = Wn + rw * nH;
  const unsigned short* axb = xb + (size_t)arow * nH + q * 8;
  const unsigned short* agb = gbuf + (size_t)arow * nH + q * 8;
  unsigned short* pkw = &pk[w][0][0];
  unsigned short* gdst = gbuf + (size_t)(m0 + mq * 16) * nH + n0 + nq * 16;
  unsigned short* xdst = xb + (size_t)(m0 + mq * 16) * nH + n0 + nq * 16;

  float hb[4], xv[4], ka[4];
  int lst[4];
#pragma unroll
  for (int ii = 0; ii < 4; ++ii) {
    hb[ii] = h0f[(size_t)(row0 + ii) * nH + col];
    xv[ii] = hb[ii];
    lst[ii] = lidx[row0 + ii];
  }
  unsigned* myc = ctr + i * 64;   // 256B-padded per-rowband barrier counter
  unsigned ph = 0;
  __syncthreads();   // weights staged

  for (int s = 0; s < nNT - 1; ++s) {
    const float dt = ts[s + 1] - ts[s];
#pragma unroll 1
    for (int stg = 0; stg < 4; ++stg) {
      // ---- mm1: zz = sigmoid(x @ Whz^T); g = zz * x ----
      ffrag acc = mm_l2(axb, wzrow, q, rx);
      float zv[4], gv[4];
#pragma unroll
      for (int ii = 0; ii < 4; ++ii) {
        zv[ii] = sigm(acc[ii]);
        gv[ii] = zv[ii] * xv[ii];
      }
      pack_store(gv, pkw, lane, gdst);
      ph += 32; rb_bar(myc, ph);
      // ---- mm2: nn = tanh(g @ Whn^T); f = (1-zz)*(nn-x); stage update ----
      acc = mm_l2(agb, wnrow, q, rx);
#pragma unroll
      for (int ii = 0; ii < 4; ++ii) {
        const float nn = tanhf(acc[ii]);
        const float fv = (1.f - zv[ii]) * (nn - xv[ii]);
        if (stg == 0)      { ka[ii] = fv;        xv[ii] = hb[ii] + 0.5f * dt * fv; }
        else if (stg == 1) { ka[ii] += 2.f * fv; xv[ii] = hb[ii] + 0.5f * dt * fv; }
        else if (stg == 2) { ka[ii] += 2.f * fv; xv[ii] = hb[ii] + dt * fv; }
        else {
          const float hn = hb[ii] + (dt * (1.f / 6.f)) * (ka[ii] + fv);
          hb[ii] = hn; xv[ii] = hn;
          if (lst[ii] == s + 1) out[(size_t)(row0 + ii) * nH + col] = hn;
        }
      }
      pack_store(xv, pkw, lane, xdst);
      ph += 32; rb_bar(myc, ph);
    }
  }
}

}  // namespace

extern "C" void kernel_launch(void* const* d_in, const int* in_sizes, int n_in,
                              void* d_out, int out_size, void* d_ws, size_t ws_size,
                              hipStream_t stream) {
  const float* Hs   = (const float*)d_in[0];
  const float* ts   = (const float*)d_in[1];
  const int*   lidx = (const int*)d_in[2];
  const int*   llm  = (const int*)d_in[3];
  const float* eps  = (const float*)d_in[4];
  const float* emb  = (const float*)d_in[5];
  const float* Wih  = (const float*)d_in[6];
  const float* Whh  = (const float*)d_in[7];
  const float* bih  = (const float*)d_in[8];
  const float* bhh  = (const float*)d_in[9];
  const float* aw   = (const float*)d_in[10];
  const float* Wmu  = (const float*)d_in[11];
  const float* bmu  = (const float*)d_in[12];
  const float* Wvar = (const float*)d_in[13];
  const float* bvar = (const float*)d_in[14];
  const float* Whz  = (const float*)d_in[15];
  const float* Whn  = (const float*)d_in[16];

  float* out_last = (float*)d_out;
  float* out_mask = out_last + (size_t)nB * nH;

  char* p = (char*)d_ws;
  auto alloc = [&](size_t bytes) {
    void* r = p; p += (bytes + 255) & ~(size_t)255; return r;
  };
  unsigned short* Whh_b  = (unsigned short*)alloc((size_t)3 * nH * nH * 2);
  unsigned short* Wih_b  = (unsigned short*)alloc((size_t)3 * nH * nD * 2);
  unsigned short* Wmu_b  = (unsigned short*)alloc((size_t)nH * nH * 2);
  unsigned short* Wvar_b = (unsigned short*)alloc((size_t)nH * nH * 2);
  unsigned short* Whz_b  = (unsigned short*)alloc((size_t)nH * nH * 2);
  unsigned short* Whn_b  = (unsigned short*)alloc((size_t)nH * nH * 2);
  unsigned short* ve_b   = (unsigned short*)alloc((size_t)nB * nT * nD * 2);
  unsigned short* hs_b   = (unsigned short*)alloc((size_t)nB * nT * nH * 2);
  float* h0f             = (float*)alloc((size_t)nB * nH * 4);
  unsigned short* h0b    = (unsigned short*)alloc((size_t)nB * nH * 2);
  unsigned short* h1b    = (unsigned short*)alloc((size_t)nB * nH * 2);
  unsigned short* gb     = (unsigned short*)alloc((size_t)nB * nH * 2);
  unsigned short* hencb  = (unsigned short*)alloc((size_t)nB * nH * 2);
  unsigned* ctr          = (unsigned*)alloc(8192);   // barriers + rank ctrs

  hipMemsetAsync(h0b, 0, (size_t)nB * nH * 2, stream);   // GRU h0 = 0
  hipMemsetAsync(ctr, 0, 8192, stream);                  // all counters

  auto cvt = [&](const float* s, unsigned short* d, int n) {
    k_cvt<<<n / 1024, 256, 0, stream>>>(s, d, n);
  };
  cvt(Whh, Whh_b, 3 * nH * nH);
  cvt(Wih, Wih_b, 3 * nH * nD);
  cvt(Wmu, Wmu_b, nH * nH);
  cvt(Wvar, Wvar_b, nH * nH);
  cvt(Whz, Whz_b, nH * nH);
  cvt(Whn, Whn_b, nH * nH);

  k_embed<<<nB, 256, 0, stream>>>(Hs, emb, ve_b);
  k_mask<<<dim3((nC + 255) / 256, nB), 256, 0, stream>>>(llm, out_mask);

  // entire 64-step GRU in one persistent kernel (1 CP barrier per step)
  k_gru_persist<<<256, 256, 0, stream>>>(Whh_b, Wih_b, bih, bhh, ve_b,
                                         h0b, h1b, hs_b, ctr);

  k_attn<<<nB, 256, 0, stream>>>(hs_b, aw, hencb);
  const dim3 gg(nB / 32, nH / 32);  // 8 x 32 = 256 blocks
  // z0 -> h0f (f32 base state) + h0b (bf16, first mm1 A-operand)
  k_vae<<<gg, 256, 0, stream>>>(hencb, Wmu_b, Wvar_b, bmu, bvar, eps,
                                h0f, h0b, lidx, out_last);

  // entire 100-step RK4 GRU-ODE in one persistent kernel (round 8/14 proven)
  k_ode_persist<<<256, 256, 0, stream>>>(Whz_b, Whn_b, h0f, h0b, gb, ts, lidx,
                                         out_last, ctr);
}